// Round 16
// baseline (327.115 us; speedup 1.0000x reference)
//
#include <hip/hip_runtime.h>
#include <math.h>

#define N_ROWS 8192
#define K_DIM  7168
#define N_EXP  256
#define NTALL  224               // total K-chunks of 32

#define FLAG_CAP 2048

typedef unsigned int u32;
typedef short short8 __attribute__((ext_vector_type(8)));
typedef float f32x4  __attribute__((ext_vector_type(4)));

__device__ __forceinline__ void gload_lds16(const void* g, void* l) {
    __builtin_amdgcn_global_load_lds(
        (const __attribute__((address_space(1))) u32*)(g),
        (__attribute__((address_space(3))) u32*)(l), 16, 0, 0);
}
__device__ __forceinline__ void gload_lds4(const void* g, void* l) {
    __builtin_amdgcn_global_load_lds(
        (const __attribute__((address_space(1))) u32*)(g),
        (__attribute__((address_space(3))) u32*)(l), 4, 0, 0);
}

__device__ __forceinline__ void split_bf16(float v, unsigned short& hi, unsigned short& lo) {
    u32 ub = __float_as_uint(v);
    u32 hb = (ub + 0x7FFFu + ((ub >> 16) & 1u)) >> 16;
    float hv = __uint_as_float(hb << 16);
    float r  = v - hv;
    u32 rb2 = __float_as_uint(r);
    u32 lb2 = (rb2 + 0x7FFFu + ((rb2 >> 16) & 1u)) >> 16;
    hi = (unsigned short)hb;
    lo = (unsigned short)lb2;
}

// ============ p0: W -> split bf16 image in ws (MFMA-ready tiled layout) =====
__global__ __launch_bounds__(128) void p0_wprep(
    const float* __restrict__ W, unsigned short* __restrict__ wimg)
{
    const int bid = blockIdx.x;            // c*8 + h*4 + kg
    const int c  = bid >> 3;
    const int h  = (bid >> 2) & 1;
    const int kg = bid & 3;
    const int n  = threadIdx.x;            // 0..127

    short8 h8, l8;
    #pragma unroll
    for (int j = 0; j < 8; ++j) {
        float v = W[(size_t)(c * 32 + kg * 8 + j) * N_EXP + h * 128 + n];
        unsigned short hi, lo;
        split_bf16(v, hi, lo);
        h8[j] = (short)hi; l8[j] = (short)lo;
    }
    size_t base = (size_t)(c * 2 + h) * 8192;
    *(short8*)(wimg + base + (size_t)(kg * 128 + n) * 8)        = h8;
    *(short8*)(wimg + base + 4096 + (size_t)(kg * 128 + n) * 8) = l8;
}

// ============ p1_mfma2: BM=128, BN=128, ksplit=4, wave tile 64x32 (r14) =====
#define N2_AHI 8192
#define N2_BUF 16512
#define N2_KC  56

__global__ __launch_bounds__(512, 4) void p1_mfma2(
    const float* __restrict__ x, const unsigned short* __restrict__ wimg,
    float* __restrict__ d0, float* __restrict__ d1,
    float* __restrict__ d2, float* __restrict__ d3)
{
    __shared__ unsigned short lds[2][N2_BUF];   // 66048 B

    const int tid  = threadIdx.x;
    const int lane = tid & 63;
    const int wid  = tid >> 6;
    const int wrow = wid >> 2;            // 0..1 (64 rows each)
    const int wcol = wid & 3;             // 0..3 (32 cols each)

    const int bid = blockIdx.x;
    const int xcd = bid & 7;
    const int cbi = xcd >> 2;
    const int ks  = xcd & 3;
    const int rb  = (bid >> 3) * 128;
    const int cb  = cbi * 128;
    const int kbase = ks * N2_KC;

    const unsigned short* wsrc = wimg + (size_t)cbi * 8192 + (size_t)kbase * 16384;

    const int xrow = tid >> 2;            // 0..127
    const int xkg  = tid & 3;
    const float* xg = x + (size_t)(rb + xrow) * K_DIM + (size_t)kbase * 32 + xkg * 8;

    const int arow = lane & 15;
    const int akg  = lane >> 4;

    f32x4 acc[4][2] = {};
    float4 x0a, x0b, x1a, x1b, x2a, x2b;

    auto loadB = [&](int c, int slot) {
        const unsigned short* src = wsrc + (size_t)c * 16384;
        gload_lds16(src + (size_t)tid * 8,        &lds[slot][tid * 8]);
        gload_lds16(src + 4096 + (size_t)tid * 8, &lds[slot][4096 + tid * 8]);
    };

    auto writeA = [&](const float4& a, const float4& b, int slot) {
        u32 u[8] = {__float_as_uint(a.x), __float_as_uint(a.y),
                    __float_as_uint(a.z), __float_as_uint(a.w),
                    __float_as_uint(b.x), __float_as_uint(b.y),
                    __float_as_uint(b.z), __float_as_uint(b.w)};
        float v[8] = {a.x, a.y, a.z, a.w, b.x, b.y, b.z, b.w};
        union { u32 w[4]; short8 s; } hu, lu;
        float r[8];
        #pragma unroll
        for (int i = 0; i < 4; ++i)
            hu.w[i] = (u[2*i] >> 16) | (u[2*i+1] & 0xffff0000u);
        #pragma unroll
        for (int i = 0; i < 8; ++i)
            r[i] = v[i] - __uint_as_float(u[i] & 0xffff0000u);
        #pragma unroll
        for (int i = 0; i < 4; ++i)
            asm("v_cvt_pk_bf16_f32 %0, %1, %2" : "=v"(lu.w[i]) : "v"(r[2*i]), "v"(r[2*i+1]));
        const int off = N2_AHI + xkg * 1040 + xrow * 8;
        *(short8*)&lds[slot][off]        = hu.s;
        *(short8*)&lds[slot][off + 4160] = lu.s;
    };

    auto comp = [&](int slot) {
        const unsigned short* L = lds[slot];
        short8 ah[4], al[4];
        #pragma unroll
        for (int m = 0; m < 4; ++m) {
            const int roff = N2_AHI + akg * 1040 + (wrow * 64 + m * 16 + arow) * 8;
            ah[m] = *(const short8*)&L[roff];
            al[m] = *(const short8*)&L[roff + 4160];
        }
        #pragma unroll
        for (int nf = 0; nf < 2; ++nf) {
            const int n = wcol * 32 + nf * 16 + arow;
            short8 bh = *(const short8*)&L[akg * 1024 + n * 8];
            short8 bl = *(const short8*)&L[4096 + akg * 1024 + n * 8];
            #pragma unroll
            for (int m = 0; m < 4; ++m) {
                acc[m][nf] = __builtin_amdgcn_mfma_f32_16x16x32_bf16(ah[m], bh, acc[m][nf], 0, 0, 0);
                acc[m][nf] = __builtin_amdgcn_mfma_f32_16x16x32_bf16(ah[m], bl, acc[m][nf], 0, 0, 0);
                acc[m][nf] = __builtin_amdgcn_mfma_f32_16x16x32_bf16(al[m], bh, acc[m][nf], 0, 0, 0);
            }
        }
    };

#define STEP2(C, CS, WS, XW0, XW1, XL0, XL1) {                                \
    asm volatile("s_waitcnt vmcnt(2)" ::: "memory");                          \
    asm volatile("s_barrier" ::: "memory");                                   \
    writeA(XW0, XW1, WS);                                                     \
    loadB((C) + 1, WS);                                                       \
    { int cx = (C) + 3; if (cx > N2_KC - 1) cx = N2_KC - 1;                   \
      XL0 = *(const float4*)(xg + (size_t)cx * 32);                           \
      XL1 = *(const float4*)(xg + (size_t)cx * 32 + 4); }                     \
    __builtin_amdgcn_sched_barrier(0);                                        \
    comp(CS);                                                                 \
    asm volatile("s_waitcnt lgkmcnt(0)" ::: "memory"); }

    x0a = *(const float4*)(xg);
    x0b = *(const float4*)(xg + 4);
    asm volatile("s_waitcnt vmcnt(0)" ::: "memory");
    x1a = *(const float4*)(xg + 32);
    x1b = *(const float4*)(xg + 36);
    __builtin_amdgcn_sched_barrier(0);
    loadB(0, 0);
    __builtin_amdgcn_sched_barrier(0);
    x2a = *(const float4*)(xg + 64);
    x2b = *(const float4*)(xg + 68);
    __builtin_amdgcn_sched_barrier(0);
    writeA(x0a, x0b, 0);
    asm volatile("s_waitcnt lgkmcnt(0)" ::: "memory");

    for (int c = 0; c < 54; c += 6) {
        STEP2(c + 0, 0, 1, x1a, x1b, x0a, x0b);
        STEP2(c + 1, 1, 0, x2a, x2b, x1a, x1b);
        STEP2(c + 2, 0, 1, x0a, x0b, x2a, x2b);
        STEP2(c + 3, 1, 0, x1a, x1b, x0a, x0b);
        STEP2(c + 4, 0, 1, x2a, x2b, x1a, x1b);
        STEP2(c + 5, 1, 0, x0a, x0b, x2a, x2b);
    }
    STEP2(54, 0, 1, x1a, x1b, x0a, x0b);
#undef STEP2
    asm volatile("s_waitcnt vmcnt(0)" ::: "memory");
    asm volatile("s_barrier" ::: "memory");
    comp(1);                               // chunk 55

    float* o = (ks == 0) ? d0 : (ks == 1) ? d1 : (ks == 2) ? d2 : d3;
    #pragma unroll
    for (int m = 0; m < 4; ++m)
        #pragma unroll
        for (int nf = 0; nf < 2; ++nf) {
            const int col = cb + wcol * 32 + nf * 16 + arow;
            const int r0  = rb + wrow * 64 + m * 16 + akg * 4;
            #pragma unroll
            for (int r = 0; r < 4; ++r)
                o[(size_t)(r0 + r) * N_EXP + col] = acc[m][nf][r];
        }
}

// ============ p1_mfma: r13-proven fallback (BM=64, ring-3, split-K 2) =======
#define A_HI   8192
#define BUFU16 12352

__global__ __launch_bounds__(512) void p1_mfma(
    const float* __restrict__ x, const unsigned short* __restrict__ wimg,
    float* __restrict__ dst0, float* __restrict__ dst1, int split)
{
    __shared__ unsigned short lds[3][BUFU16];

    const int tid  = threadIdx.x;
    const int lane = tid & 63;
    const int wid  = tid >> 6;
    const int wrow = wid >> 2;
    const int wcol = wid & 3;

    const int bid = blockIdx.x;
    const int xcd = bid & 7;
    const int cbi = xcd >> 2;
    int rtile, ks, kc;
    if (split) { ks = (xcd >> 1) & 1; rtile = (xcd & 1) * 64 + (bid >> 3); kc = 112; }
    else       { ks = 0;              rtile = (xcd & 3) * 32 + (bid >> 3); kc = NTALL; }
    const int rb    = rtile * 64;
    const int cb    = cbi * 128;
    const int kbase = ks * 112;

    const unsigned short* wsrc = wimg + (size_t)cbi * 8192 + (size_t)kbase * 16384;

    const int xrow  = tid >> 3;
    const int xk4   = (tid & 7) * 4;
    const int akg_w = xk4 >> 3;
    const int ajh   = xk4 & 7;
    const float* xg = x + (size_t)(rb + xrow) * K_DIM + (size_t)kbase * 32 + xk4;

    const int arow = lane & 15;
    const int akg  = lane >> 4;

    f32x4 acc[2][2] = {};
    float4 xr0, xr1, xr2;

    auto gloadB = [&](int c, int slot) {
        const unsigned short* src = wsrc + (size_t)c * 16384;
        gload_lds16(src + (size_t)tid * 8,        &lds[slot][tid * 8]);
        gload_lds16(src + 4096 + (size_t)tid * 8, &lds[slot][4096 + tid * 8]);
    };

    auto writeA = [&](const float4& v4, int slot) {
        u32 u0 = __float_as_uint(v4.x), u1 = __float_as_uint(v4.y);
        u32 u2 = __float_as_uint(v4.z), u3 = __float_as_uint(v4.w);
        u32 h01 = (u0 >> 16) | (u1 & 0xffff0000u);
        u32 h23 = (u2 >> 16) | (u3 & 0xffff0000u);
        float r0 = v4.x - __uint_as_float(u0 & 0xffff0000u);
        float r1 = v4.y - __uint_as_float(u1 & 0xffff0000u);
        float r2 = v4.z - __uint_as_float(u2 & 0xffff0000u);
        float r3 = v4.w - __uint_as_float(u3 & 0xffff0000u);
        u32 l01, l23;
        asm("v_cvt_pk_bf16_f32 %0, %1, %2" : "=v"(l01) : "v"(r0), "v"(r1));
        asm("v_cvt_pk_bf16_f32 %0, %1, %2" : "=v"(l23) : "v"(r2), "v"(r3));
        uint2 hv = {h01, h23}, lv = {l01, l23};
        const int off = A_HI + akg_w * 520 + xrow * 8 + ajh;
        *(uint2*)&lds[slot][off]        = hv;
        *(uint2*)&lds[slot][off + 2080] = lv;
    };

    auto comp = [&](int slot) {
        const unsigned short* L = lds[slot];
        short8 ah[2], al[2];
        #pragma unroll
        for (int m = 0; m < 2; ++m) {
            const int roff = A_HI + akg * 520 + (wrow * 32 + m * 16 + arow) * 8;
            ah[m] = *(const short8*)&L[roff];
            al[m] = *(const short8*)&L[roff + 2080];
        }
        #pragma unroll
        for (int nf = 0; nf < 2; ++nf) {
            const int n = wcol * 32 + nf * 16 + arow;
            short8 bh = *(const short8*)&L[akg * 1024 + n * 8];
            short8 bl = *(const short8*)&L[4096 + akg * 1024 + n * 8];
            #pragma unroll
            for (int m = 0; m < 2; ++m) {
                acc[m][nf] = __builtin_amdgcn_mfma_f32_16x16x32_bf16(ah[m], bh, acc[m][nf], 0, 0, 0);
                acc[m][nf] = __builtin_amdgcn_mfma_f32_16x16x32_bf16(ah[m], bl, acc[m][nf], 0, 0, 0);
                acc[m][nf] = __builtin_amdgcn_mfma_f32_16x16x32_bf16(al[m], bh, acc[m][nf], 0, 0, 0);
            }
        }
    };

    xr0 = *(const float4*)(xg);
    xr1 = *(const float4*)(xg + 32);
    xr2 = *(const float4*)(xg + 64);
    __builtin_amdgcn_sched_barrier(0);
    gloadB(0, 0);
    gloadB(1, 1);
    __builtin_amdgcn_sched_barrier(0);
    asm volatile("s_waitcnt vmcnt(0)" ::: "memory");
    writeA(xr0, 0);
    asm volatile("s_waitcnt lgkmcnt(0)" ::: "memory");
    asm volatile("s_barrier" ::: "memory");

#define STEPA(C, I, XW, XL) {                                                 \
    asm volatile("s_waitcnt vmcnt(3)" ::: "memory");                          \
    writeA(XW, ((I) + 1) % 3);                                                \
    asm volatile("s_waitcnt lgkmcnt(0)" ::: "memory");                        \
    asm volatile("s_barrier" ::: "memory");                                   \
    { int cx = (C) + 3; if (cx > kc - 1) cx = kc - 1;                         \
      XL = *(const float4*)(xg + (size_t)cx * 32); }                          \
    __builtin_amdgcn_sched_barrier(0);                                        \
    { int cbv = (C) + 2; if (cbv > kc - 1) cbv = kc - 1;                      \
      gloadB(cbv, ((I) + 2) % 3); }                                           \
    __builtin_amdgcn_sched_barrier(0);                                        \
    comp(I); }

    const int m3 = kc - (kc % 3);
    for (int c = 0; c < m3; c += 3) {
        STEPA(c,     0, xr1, xr0);
        STEPA(c + 1, 1, xr2, xr1);
        STEPA(c + 2, 2, xr0, xr2);
    }
#undef STEPA

    for (int t = m3; t < kc; ++t) {
        float4 xt = *(const float4*)(xg + (size_t)t * 32);
        asm volatile("s_waitcnt vmcnt(0)" ::: "memory");
        __syncthreads();
        writeA(xt, t % 3);
        asm volatile("s_waitcnt lgkmcnt(0)" ::: "memory");
        __syncthreads();
        comp(t % 3);
    }

    float* o = ks ? dst1 : dst0;
    #pragma unroll
    for (int m = 0; m < 2; ++m)
        #pragma unroll
        for (int nf = 0; nf < 2; ++nf) {
            const int col = cb + wcol * 32 + nf * 16 + arow;
            const int r0  = rb + wrow * 32 + m * 16 + akg * 4;
            #pragma unroll
            for (int r = 0; r < 4; ++r)
                o[(size_t)(r0 + r) * N_EXP + col] = acc[m][nf][r];
        }
}

// ============ p1 fallback (fp32 VALU, proven r5) ============================
#define F1_BM 32
#define F1_BN 64
#define F1_BK 32
#define F1_NT (K_DIM / F1_BK)

__global__ __launch_bounds__(256, 4) void p1_fp32(
    const float* __restrict__ x, const float* __restrict__ W,
    float* __restrict__ logits)
{
    __shared__ float xs[2][F1_BK * F1_BM];
    __shared__ float ws[2][F1_BK * F1_BN];

    const int tid  = threadIdx.x;
    const int w    = tid >> 6;
    const int lane = tid & 63;
    const int trow = tid >> 5;
    const int tcol = tid & 31;
    const int rb   = blockIdx.y * F1_BM;
    const int cb   = blockIdx.x * F1_BN;

    float acc[4][2] = {};
    const float* gx[4];
    const float* gw[2];
    #pragma unroll
    for (int q = 0; q < 4; ++q) {
        int L = (w * 4 + q) * 64 + lane;
        gx[q] = x + (size_t)(rb + (L & 31)) * K_DIM + (L >> 5);
    }
    #pragma unroll
    for (int q = 0; q < 2; ++q) {
        int F = ((w * 2 + q) * 64 + lane) * 4;
        gw[q] = W + (size_t)(F >> 6) * N_EXP + cb + (F & 63);
    }
    auto stage = [&](int buf) {
        #pragma unroll
        for (int q = 0; q < 2; ++q) gload_lds16(gw[q], &ws[buf][(w * 2 + q) * 256]);
        #pragma unroll
        for (int q = 0; q < 4; ++q) gload_lds4(gx[q], &xs[buf][(w * 4 + q) * 64]);
        #pragma unroll
        for (int q = 0; q < 2; ++q) gw[q] += (size_t)F1_BK * N_EXP;
        #pragma unroll
        for (int q = 0; q < 4; ++q) gx[q] += F1_BK;
    };
    auto compute = [&](int buf) {
        #pragma unroll
        for (int kk = 0; kk < F1_BK; ++kk) {
            float4 av = *(const float4*)&xs[buf][kk * 32 + trow * 4];
            float2 bv = *(const float2*)&ws[buf][kk * 64 + tcol * 2];
            float aa[4] = {av.x, av.y, av.z, av.w};
            float bb[2] = {bv.x, bv.y};
            #pragma unroll
            for (int i = 0; i < 4; ++i)
                #pragma unroll
                for (int jq = 0; jq < 2; ++jq)
                    acc[i][jq] = fmaf(aa[i], bb[jq], acc[i][jq]);
        }
    };
    stage(0);
    asm volatile("s_waitcnt vmcnt(0)" ::: "memory");
    __syncthreads();
    int cur = 0;
    for (int t = 0; t < F1_NT; ++t) {
        if (t + 1 < F1_NT) stage(cur ^ 1);
        compute(cur);
        asm volatile("s_waitcnt vmcnt(0)" ::: "memory");
        __syncthreads();
        cur ^= 1;
    }
    #pragma unroll
    for (int i = 0; i < 4; ++i) {
        float2 o = {acc[i][0], acc[i][1]};
        *(float2*)(logits + (size_t)(rb + trow * 4 + i) * N_EXP + cb + tcol * 2) = o;
    }
}

// ============ p2: sum npart partials + route + flag (1 wave / row) ==========
__global__ __launch_bounds__(256) void p2_route(
    float* __restrict__ sc, const float* __restrict__ pk1,
    const float* __restrict__ pk2, const float* __restrict__ pk3,
    const float* __restrict__ bias,
    float* __restrict__ out_idx, float* __restrict__ out_w,
    int* __restrict__ flag_cnt, int* __restrict__ flag_list,
    int npart, float thS, float thG)
{
    const int lane = threadIdx.x & 63;
    const int row  = blockIdx.x * 4 + (threadIdx.x >> 6);
    float* s = sc + (size_t)row * N_EXP;
    const int ib = lane * 4;

    float4 l4 = *(const float4*)&s[ib];
    if (npart >= 2) {
        float4 o4 = *(const float4*)(pk1 + (size_t)row * N_EXP + ib);
        l4.x += o4.x; l4.y += o4.y; l4.z += o4.z; l4.w += o4.w;
    }
    if (npart >= 4) {
        float4 o4 = *(const float4*)(pk2 + (size_t)row * N_EXP + ib);
        l4.x += o4.x; l4.y += o4.y; l4.z += o4.z; l4.w += o4.w;
        float4 p4 = *(const float4*)(pk3 + (size_t)row * N_EXP + ib);
        l4.x += p4.x; l4.y += p4.y; l4.z += p4.z; l4.w += p4.w;
    }
    float4 s4;
    s4.x = 1.0f / (1.0f + expf(-l4.x));
    s4.y = 1.0f / (1.0f + expf(-l4.y));
    s4.z = 1.0f / (1.0f + expf(-l4.z));
    s4.w = 1.0f / (1.0f + expf(-l4.w));
    *(float4*)&s[ib] = s4;

    float4 b4 = *(const float4*)&bias[ib];
    float v0 = s4.x + b4.x, v1 = s4.y + b4.y, v2 = s4.z + b4.z, v3 = s4.w + b4.w;

    float a = fmaxf(v0, v1), b = fminf(v0, v1);
    float c = fmaxf(v2, v3), d = fminf(v2, v3);
    float m1 = fmaxf(a, c);
    float m2 = fmaxf(fminf(a, c), fmaxf(b, d));
    #pragma unroll
    for (int off = 1; off <= 4; off <<= 1) {
        float o1 = __shfl_xor(m1, off);
        float o2 = __shfl_xor(m2, off);
        float hi = fmaxf(m1, o1), lo = fminf(m1, o1);
        m2 = fmaxf(lo, fmaxf(m2, o2));
        m1 = hi;
    }
    float gsum = m1 + m2;
    float gv[8];
    #pragma unroll
    for (int g = 0; g < 8; ++g) gv[g] = __shfl(gsum, g * 8);

    unsigned gmask = 0;
    float g4 = 0.f, g5 = 0.f;
    #pragma unroll
    for (int t = 0; t < 5; ++t) {
        float best = -INFINITY; int bg = 0;
        #pragma unroll
        for (int g = 0; g < 8; ++g)
            if (!((gmask >> g) & 1) && gv[g] > best) { best = gv[g]; bg = g; }
        if (t < 4) { gmask |= 1u << bg; if (t == 3) g4 = best; }
        else g5 = best;
    }
    bool flag = (g4 - g5) < thG;

    bool sel = (gmask >> (lane >> 3)) & 1;
    float c0 = sel ? v0 : -INFINITY;
    float c1 = sel ? v1 : -INFINITY;
    float c2 = sel ? v2 : -INFINITY;
    float c3 = sel ? v3 : -INFINITY;

    float tvv[9]; int tii[9];
    #pragma unroll
    for (int r = 0; r < 9; ++r) {
        float lv = c0; int li = ib;
        if (c1 > lv) { lv = c1; li = ib + 1; }
        if (c2 > lv) { lv = c2; li = ib + 2; }
        if (c3 > lv) { lv = c3; li = ib + 3; }
        #pragma unroll
        for (int off = 1; off < 64; off <<= 1) {
            float ov = __shfl_xor(lv, off);
            int   oi = __shfl_xor(li, off);
            if (ov > lv || (ov == lv && oi < li)) { lv = ov; li = oi; }
        }
        tvv[r] = lv; tii[r] = li;
        if      (li == ib)     c0 = -INFINITY;
        else if (li == ib + 1) c1 = -INFINITY;
        else if (li == ib + 2) c2 = -INFINITY;
        else if (li == ib + 3) c3 = -INFINITY;
    }
    #pragma unroll
    for (int k = 0; k < 8; ++k)
        if (tvv[k] - tvv[k + 1] < thS) flag = true;

    float wv[8]; double wsum = 0.0;
    #pragma unroll
    for (int k = 0; k < 8; ++k) {
        int t = tii[k];
        int jq = t & 3;
        float svv = (jq == 0) ? s4.x : (jq == 1) ? s4.y : (jq == 2) ? s4.z : s4.w;
        float wk = __shfl(svv, t >> 2);
        wv[k] = wk; wsum += (double)wk;
    }
    double inv = 2.5 / (wsum + 1e-20);
    if (lane == 0) {
        #pragma unroll
        for (int k = 0; k < 8; ++k) {
            out_idx[(size_t)row * 8 + k] = (float)tii[k];
            out_w[(size_t)row * 8 + k]   = (float)((double)wv[k] * inv);
        }
        if (flag) {
            int pz = atomicAdd(flag_cnt, 1);
            if (pz < FLAG_CAP) flag_list[pz] = row;
        }
    }
}

// ============ p3a: fp64 partials, 4 rows/block, strided slot-groups =========
#define P3_SL 8
#define P3_SK (K_DIM / P3_SL)   // 896
#define P3_RG 4                 // rows per group

__global__ __launch_bounds__(256) void p3a_partial(
    const float* __restrict__ x, const float* __restrict__ W,
    const int* __restrict__ flag_cnt, const int* __restrict__ flag_list,
    double* __restrict__ partials, int cap)
{
    int count = *flag_cnt;
    if (count > cap) count = cap;
    const int base  = blockIdx.x >> 3;    // 0..255 slot-group lane
    const int slice = blockIdx.x & 7;
    const int tid   = threadIdx.x;        // expert e

    __shared__ float xls[P3_RG][P3_SK];   // 14 KB
    __shared__ int   rid[P3_RG];

    const float* wp = W + (size_t)(slice * P3_SK) * N_EXP + tid;

    for (int sg = base; sg * P3_RG < count; sg += 256) {
        const int r0 = sg * P3_RG;
        const int nr = min(P3_RG, count - r0);

        if (tid < P3_RG) rid[tid] = flag_list[r0 + min(tid, nr - 1)];
        __syncthreads();

        // stage 4 rows x 896 floats (896 float4 total)
        #pragma unroll
        for (int q = 0; q < 4; ++q) {
            int idx = q * 256 + tid;          // 0..1023
            if (idx < P3_RG * (P3_SK / 4)) {
                int r = idx / (P3_SK / 4), j = idx % (P3_SK / 4);
                *(float4*)&xls[r][j * 4] =
                    *(const float4*)(x + (size_t)rid[r] * K_DIM + slice * P3_SK + j * 4);
            }
        }
        __syncthreads();

        double a0 = 0.0, a1 = 0.0, a2 = 0.0, a3 = 0.0;
        #pragma unroll 2
        for (int j = 0; j < P3_SK; ++j) {
            double wj = (double)wp[(size_t)j * N_EXP];
            a0 = fma((double)xls[0][j], wj, a0);
            a1 = fma((double)xls[1][j], wj, a1);
            a2 = fma((double)xls[2][j], wj, a2);
            a3 = fma((double)xls[3][j], wj, a3);
        }
        double av[4] = {a0, a1, a2, a3};
        #pragma unroll
        for (int r = 0; r < P3_RG; ++r)
            if (r < nr)
                partials[((size_t)(r0 + r) * P3_SL + slice) * N_EXP + tid] = av[r];
        __syncthreads();
    }
}

// ============ p3b: reduce + fp64 route, strided slots =======================
__global__ __launch_bounds__(256) void p3b_route(
    const double* __restrict__ partials, const float* __restrict__ bias,
    float* __restrict__ out_idx, float* __restrict__ out_w,
    const int* __restrict__ flag_cnt, const int* __restrict__ flag_list, int cap)
{
    int count = *flag_cnt;
    if (count > cap) count = cap;
    const int tid = threadIdx.x;

    __shared__ double scl[N_EXP];
    __shared__ float  bias_s[N_EXP];
    bias_s[tid] = bias[tid];

    for (int slot = blockIdx.x; slot < count; slot += 256) {
        const int row = flag_list[slot];

        const double* pp = partials + (size_t)slot * P3_SL * N_EXP + tid;
        double l = 0.0;
        #pragma unroll
        for (int sx = 0; sx < P3_SL; ++sx) l += pp[(size_t)sx * N_EXP];
        scl[tid] = 1.0 / (1.0 + exp(-l));
        __syncthreads();

        if (tid < 64) {
            const int lane = tid;
            const int ib = lane * 4;
            double s0 = scl[ib], s1 = scl[ib + 1], s2 = scl[ib + 2], s3 = scl[ib + 3];
            double v0 = s0 + (double)bias_s[ib];
            double v1 = s1 + (double)bias_s[ib + 1];
            double v2 = s2 + (double)bias_s[ib + 2];
            double v3 = s3 + (double)bias_s[ib + 3];

            double a = fmax(v0, v1), b = fmin(v0, v1);
            double c = fmax(v2, v3), d = fmin(v2, v3);
            double m1 = fmax(a, c);
            double m2 = fmax(fmin(a, c), fmax(b, d));
            #pragma unroll
            for (int off = 1; off <= 4; off <<= 1) {
                double o1 = __shfl_xor(m1, off);
                double o2 = __shfl_xor(m2, off);
                double hi = fmax(m1, o1), lo = fmin(m1, o1);
                m2 = fmax(lo, fmax(m2, o2));
                m1 = hi;
            }
            double gsum = m1 + m2;
            double gvv[8];
            #pragma unroll
            for (int g = 0; g < 8; ++g) gvv[g] = __shfl(gsum, g * 8);

            unsigned gmask = 0;
            #pragma unroll
            for (int t = 0; t < 4; ++t) {
                double best = -1e300; int bg = 0;
                #pragma unroll
                for (int g = 0; g < 8; ++g)
                    if (!((gmask >> g) & 1) && gvv[g] > best) { best = gvv[g]; bg = g; }
                gmask |= 1u << bg;
            }

            bool sel = (gmask >> (lane >> 3)) & 1;
            double c0 = sel ? v0 : -1e300;
            double c1 = sel ? v1 : -1e300;
            double c2 = sel ? v2 : -1e300;
            double c3 = sel ? v3 : -1e300;

            int tii[8];
            #pragma unroll
            for (int r = 0; r < 8; ++r) {
                double lv = c0; int li = ib;
                if (c1 > lv) { lv = c1; li = ib + 1; }
                if (c2 > lv) { lv = c2; li = ib + 2; }
                if (c3 > lv) { lv = c3; li = ib + 3; }
                #pragma unroll
                for (int off = 1; off < 64; off <<= 1) {
                    double ov = __shfl_xor(lv, off);
                    int    oi = __shfl_xor(li, off);
                    if (ov > lv || (ov == lv && oi < li)) { lv = ov; li = oi; }
                }
                tii[r] = li;
                if      (li == ib)     c0 = -1e300;
                else if (li == ib + 1) c1 = -1e300;
                else if (li == ib + 2) c2 = -1e300;
                else if (li == ib + 3) c3 = -1e300;
            }

            double wv[8]; double wsum = 0.0;
            #pragma unroll
            for (int k = 0; k < 8; ++k) {
                int t = tii[k];
                int jq = t & 3;
                double svv = (jq == 0) ? s0 : (jq == 1) ? s1 : (jq == 2) ? s2 : s3;
                double wk = __shfl(svv, t >> 2);
                wv[k] = wk; wsum += wk;
            }
            double inv = 2.5 / (wsum + 1e-20);
            if (lane == 0) {
                #pragma unroll
                for (int k = 0; k < 8; ++k) {
                    out_idx[(size_t)row * 8 + k] = (float)tii[k];
                    out_w[(size_t)row * 8 + k]   = (float)(wv[k] * inv);
                }
            }
        }
        __syncthreads();
    }
}

extern "C" void kernel_launch(void* const* d_in, const int* in_sizes, int n_in,
                              void* d_out, int out_size, void* d_ws, size_t ws_size,
                              hipStream_t stream) {
    const float* x    = (const float*)d_in[0];
    const float* W    = (const float*)d_in[1];
    const float* bias = (const float*)d_in[2];

    float* out     = (float*)d_out;
    float* out_idx = out;
    float* out_w   = out + N_ROWS * 8;
    float* out_s   = out + N_ROWS * 16;

    int* flag_cnt  = (int*)d_ws;
    int* flag_list = (int*)d_ws + 4;

    const size_t WIMG_OFF  = 65536;
    const size_t WIMG_SIZE = (size_t)NTALL * 32768;        // 7.0 MiB
    const size_t PK_OFF    = WIMG_OFF + WIMG_SIZE;
    const size_t PK_SIZE   = (size_t)N_ROWS * N_EXP * 4;   // 8 MiB

    bool m4 = ws_size >= PK_OFF + 3 * PK_SIZE;
    bool m2 = ws_size >= PK_OFF + PK_SIZE;
    bool m1 = ws_size >= PK_OFF;

    long long avail = (long long)ws_size - (long long)PK_OFF;
    int cap = (avail > 0) ? (int)(avail / (P3_SL * N_EXP * sizeof(double))) : 0;
    if (cap > FLAG_CAP) cap = FLAG_CAP;

    (void)hipMemsetAsync(flag_cnt, 0, sizeof(int), stream);

    unsigned short* wimg = (unsigned short*)((char*)d_ws + WIMG_OFF);
    float* pk1 = (float*)((char*)d_ws + PK_OFF);
    float* pk2 = pk1 + (size_t)N_ROWS * N_EXP;
    float* pk3 = pk2 + (size_t)N_ROWS * N_EXP;

    if (m4) {
        p0_wprep<<<NTALL * 8, 128, 0, stream>>>(W, wimg);
        p1_mfma2<<<512, 512, 0, stream>>>(x, wimg, out_s, pk1, pk2, pk3);
        p2_route<<<N_ROWS / 4, 256, 0, stream>>>(out_s, pk1, pk2, pk3, bias,
                                                 out_idx, out_w, flag_cnt, flag_list,
                                                 4, 1.2e-5f, 2.4e-5f);
    } else if (m2) {
        p0_wprep<<<NTALL * 8, 128, 0, stream>>>(W, wimg);
        p1_mfma<<<512, 512, 0, stream>>>(x, wimg, out_s, pk1, 1);
        p2_route<<<N_ROWS / 4, 256, 0, stream>>>(out_s, pk1, pk1, pk1, bias,
                                                 out_idx, out_w, flag_cnt, flag_list,
                                                 2, 1.2e-5f, 2.4e-5f);
    } else if (m1) {
        p0_wprep<<<NTALL * 8, 128, 0, stream>>>(W, wimg);
        p1_mfma<<<256, 512, 0, stream>>>(x, wimg, out_s, out_s, 0);
        p2_route<<<N_ROWS / 4, 256, 0, stream>>>(out_s, out_s, out_s, out_s, bias,
                                                 out_idx, out_w, flag_cnt, flag_list,
                                                 1, 1.2e-5f, 2.4e-5f);
    } else {
        dim3 g1(N_EXP / F1_BN, N_ROWS / F1_BM);
        p1_fp32<<<g1, 256, 0, stream>>>(x, W, out_s);
        p2_route<<<N_ROWS / 4, 256, 0, stream>>>(out_s, out_s, out_s, out_s, bias,
                                                 out_idx, out_w, flag_cnt, flag_list,
                                                 1, 6e-6f, 1.2e-5f);
    }

    if (cap >= 64) {
        double* partials = (double*)((char*)d_ws + PK_OFF);
        p3a_partial<<<2048, 256, 0, stream>>>(x, W, flag_cnt, flag_list,
                                              partials, cap);
        p3b_route<<<256, 256, 0, stream>>>(partials, bias, out_idx, out_w,
                                           flag_cnt, flag_list, cap);
    }
}

// Round 17
// 202.091 us; speedup vs baseline: 1.6187x; 1.6187x over previous
//
#include <hip/hip_runtime.h>
#include <math.h>

#define N_ROWS 8192
#define K_DIM  7168
#define N_EXP  256
#define NTALL  224               // total K-chunks of 32

#define FLAG_CAP 2048

typedef unsigned int u32;
typedef short short8 __attribute__((ext_vector_type(8)));
typedef float f32x4  __attribute__((ext_vector_type(4)));

__device__ __forceinline__ void gload_lds16(const void* g, void* l) {
    __builtin_amdgcn_global_load_lds(
        (const __attribute__((address_space(1))) u32*)(g),
        (__attribute__((address_space(3))) u32*)(l), 16, 0, 0);
}
__device__ __forceinline__ void gload_lds4(const void* g, void* l) {
    __builtin_amdgcn_global_load_lds(
        (const __attribute__((address_space(1))) u32*)(g),
        (__attribute__((address_space(3))) u32*)(l), 4, 0, 0);
}

__device__ __forceinline__ void split_bf16(float v, unsigned short& hi, unsigned short& lo) {
    u32 ub = __float_as_uint(v);
    u32 hb = (ub + 0x7FFFu + ((ub >> 16) & 1u)) >> 16;
    float hv = __uint_as_float(hb << 16);
    float r  = v - hv;
    u32 rb2 = __float_as_uint(r);
    u32 lb2 = (rb2 + 0x7FFFu + ((rb2 >> 16) & 1u)) >> 16;
    hi = (unsigned short)hb;
    lo = (unsigned short)lb2;
}

// ============ p0: W -> split bf16 image in ws (MFMA-ready tiled layout) =====
__global__ __launch_bounds__(128) void p0_wprep(
    const float* __restrict__ W, unsigned short* __restrict__ wimg)
{
    const int bid = blockIdx.x;            // c*8 + h*4 + kg
    const int c  = bid >> 3;
    const int h  = (bid >> 2) & 1;
    const int kg = bid & 3;
    const int n  = threadIdx.x;            // 0..127

    short8 h8, l8;
    #pragma unroll
    for (int j = 0; j < 8; ++j) {
        float v = W[(size_t)(c * 32 + kg * 8 + j) * N_EXP + h * 128 + n];
        unsigned short hi, lo;
        split_bf16(v, hi, lo);
        h8[j] = (short)hi; l8[j] = (short)lo;
    }
    size_t base = (size_t)(c * 2 + h) * 8192;
    *(short8*)(wimg + base + (size_t)(kg * 128 + n) * 8)        = h8;
    *(short8*)(wimg + base + 4096 + (size_t)(kg * 128 + n) * 8) = l8;
}

// ============ p1_mfma2: BM=128, BN=128, ksplit=4, wave tile 64x32 (r14) =====
#define N2_AHI 8192
#define N2_BUF 16512
#define N2_KC  56

__global__ __launch_bounds__(512, 4) void p1_mfma2(
    const float* __restrict__ x, const unsigned short* __restrict__ wimg,
    float* __restrict__ d0, float* __restrict__ d1,
    float* __restrict__ d2, float* __restrict__ d3)
{
    __shared__ unsigned short lds[2][N2_BUF];   // 66048 B

    const int tid  = threadIdx.x;
    const int lane = tid & 63;
    const int wid  = tid >> 6;
    const int wrow = wid >> 2;            // 0..1 (64 rows each)
    const int wcol = wid & 3;             // 0..3 (32 cols each)

    const int bid = blockIdx.x;
    const int xcd = bid & 7;
    const int cbi = xcd >> 2;
    const int ks  = xcd & 3;
    const int rb  = (bid >> 3) * 128;
    const int cb  = cbi * 128;
    const int kbase = ks * N2_KC;

    const unsigned short* wsrc = wimg + (size_t)cbi * 8192 + (size_t)kbase * 16384;

    const int xrow = tid >> 2;            // 0..127
    const int xkg  = tid & 3;
    const float* xg = x + (size_t)(rb + xrow) * K_DIM + (size_t)kbase * 32 + xkg * 8;

    const int arow = lane & 15;
    const int akg  = lane >> 4;

    f32x4 acc[4][2] = {};
    float4 x0a, x0b, x1a, x1b, x2a, x2b;

    auto loadB = [&](int c, int slot) {
        const unsigned short* src = wsrc + (size_t)c * 16384;
        gload_lds16(src + (size_t)tid * 8,        &lds[slot][tid * 8]);
        gload_lds16(src + 4096 + (size_t)tid * 8, &lds[slot][4096 + tid * 8]);
    };

    auto writeA = [&](const float4& a, const float4& b, int slot) {
        u32 u[8] = {__float_as_uint(a.x), __float_as_uint(a.y),
                    __float_as_uint(a.z), __float_as_uint(a.w),
                    __float_as_uint(b.x), __float_as_uint(b.y),
                    __float_as_uint(b.z), __float_as_uint(b.w)};
        float v[8] = {a.x, a.y, a.z, a.w, b.x, b.y, b.z, b.w};
        union { u32 w[4]; short8 s; } hu, lu;
        float r[8];
        #pragma unroll
        for (int i = 0; i < 4; ++i)
            hu.w[i] = (u[2*i] >> 16) | (u[2*i+1] & 0xffff0000u);
        #pragma unroll
        for (int i = 0; i < 8; ++i)
            r[i] = v[i] - __uint_as_float(u[i] & 0xffff0000u);
        #pragma unroll
        for (int i = 0; i < 4; ++i)
            asm("v_cvt_pk_bf16_f32 %0, %1, %2" : "=v"(lu.w[i]) : "v"(r[2*i]), "v"(r[2*i+1]));
        const int off = N2_AHI + xkg * 1040 + xrow * 8;
        *(short8*)&lds[slot][off]        = hu.s;
        *(short8*)&lds[slot][off + 4160] = lu.s;
    };

    auto comp = [&](int slot) {
        const unsigned short* L = lds[slot];
        short8 ah[4], al[4];
        #pragma unroll
        for (int m = 0; m < 4; ++m) {
            const int roff = N2_AHI + akg * 1040 + (wrow * 64 + m * 16 + arow) * 8;
            ah[m] = *(const short8*)&L[roff];
            al[m] = *(const short8*)&L[roff + 4160];
        }
        #pragma unroll
        for (int nf = 0; nf < 2; ++nf) {
            const int n = wcol * 32 + nf * 16 + arow;
            short8 bh = *(const short8*)&L[akg * 1024 + n * 8];
            short8 bl = *(const short8*)&L[4096 + akg * 1024 + n * 8];
            #pragma unroll
            for (int m = 0; m < 4; ++m) {
                acc[m][nf] = __builtin_amdgcn_mfma_f32_16x16x32_bf16(ah[m], bh, acc[m][nf], 0, 0, 0);
                acc[m][nf] = __builtin_amdgcn_mfma_f32_16x16x32_bf16(ah[m], bl, acc[m][nf], 0, 0, 0);
                acc[m][nf] = __builtin_amdgcn_mfma_f32_16x16x32_bf16(al[m], bh, acc[m][nf], 0, 0, 0);
            }
        }
    };

#define STEP2(C, CS, WS, XW0, XW1, XL0, XL1) {                                \
    asm volatile("s_waitcnt vmcnt(2)" ::: "memory");                          \
    asm volatile("s_barrier" ::: "memory");                                   \
    writeA(XW0, XW1, WS);                                                     \
    loadB((C) + 1, WS);                                                       \
    { int cx = (C) + 3; if (cx > N2_KC - 1) cx = N2_KC - 1;                   \
      XL0 = *(const float4*)(xg + (size_t)cx * 32);                           \
      XL1 = *(const float4*)(xg + (size_t)cx * 32 + 4); }                     \
    __builtin_amdgcn_sched_barrier(0);                                        \
    comp(CS);                                                                 \
    asm volatile("s_waitcnt lgkmcnt(0)" ::: "memory"); }

    x0a = *(const float4*)(xg);
    x0b = *(const float4*)(xg + 4);
    asm volatile("s_waitcnt vmcnt(0)" ::: "memory");
    x1a = *(const float4*)(xg + 32);
    x1b = *(const float4*)(xg + 36);
    __builtin_amdgcn_sched_barrier(0);
    loadB(0, 0);
    __builtin_amdgcn_sched_barrier(0);
    x2a = *(const float4*)(xg + 64);
    x2b = *(const float4*)(xg + 68);
    __builtin_amdgcn_sched_barrier(0);
    writeA(x0a, x0b, 0);
    asm volatile("s_waitcnt lgkmcnt(0)" ::: "memory");

    for (int c = 0; c < 54; c += 6) {
        STEP2(c + 0, 0, 1, x1a, x1b, x0a, x0b);
        STEP2(c + 1, 1, 0, x2a, x2b, x1a, x1b);
        STEP2(c + 2, 0, 1, x0a, x0b, x2a, x2b);
        STEP2(c + 3, 1, 0, x1a, x1b, x0a, x0b);
        STEP2(c + 4, 0, 1, x2a, x2b, x1a, x1b);
        STEP2(c + 5, 1, 0, x0a, x0b, x2a, x2b);
    }
    STEP2(54, 0, 1, x1a, x1b, x0a, x0b);
#undef STEP2
    asm volatile("s_waitcnt vmcnt(0)" ::: "memory");
    asm volatile("s_barrier" ::: "memory");
    comp(1);                               // chunk 55

    float* o = (ks == 0) ? d0 : (ks == 1) ? d1 : (ks == 2) ? d2 : d3;
    #pragma unroll
    for (int m = 0; m < 4; ++m)
        #pragma unroll
        for (int nf = 0; nf < 2; ++nf) {
            const int col = cb + wcol * 32 + nf * 16 + arow;
            const int r0  = rb + wrow * 64 + m * 16 + akg * 4;
            #pragma unroll
            for (int r = 0; r < 4; ++r)
                o[(size_t)(r0 + r) * N_EXP + col] = acc[m][nf][r];
        }
}

// ============ p1_mfma: r13-proven fallback (BM=64, ring-3, split-K 2) =======
#define A_HI   8192
#define BUFU16 12352

__global__ __launch_bounds__(512) void p1_mfma(
    const float* __restrict__ x, const unsigned short* __restrict__ wimg,
    float* __restrict__ dst0, float* __restrict__ dst1, int split)
{
    __shared__ unsigned short lds[3][BUFU16];

    const int tid  = threadIdx.x;
    const int lane = tid & 63;
    const int wid  = tid >> 6;
    const int wrow = wid >> 2;
    const int wcol = wid & 3;

    const int bid = blockIdx.x;
    const int xcd = bid & 7;
    const int cbi = xcd >> 2;
    int rtile, ks, kc;
    if (split) { ks = (xcd >> 1) & 1; rtile = (xcd & 1) * 64 + (bid >> 3); kc = 112; }
    else       { ks = 0;              rtile = (xcd & 3) * 32 + (bid >> 3); kc = NTALL; }
    const int rb    = rtile * 64;
    const int cb    = cbi * 128;
    const int kbase = ks * 112;

    const unsigned short* wsrc = wimg + (size_t)cbi * 8192 + (size_t)kbase * 16384;

    const int xrow  = tid >> 3;
    const int xk4   = (tid & 7) * 4;
    const int akg_w = xk4 >> 3;
    const int ajh   = xk4 & 7;
    const float* xg = x + (size_t)(rb + xrow) * K_DIM + (size_t)kbase * 32 + xk4;

    const int arow = lane & 15;
    const int akg  = lane >> 4;

    f32x4 acc[2][2] = {};
    float4 xr0, xr1, xr2;

    auto gloadB = [&](int c, int slot) {
        const unsigned short* src = wsrc + (size_t)c * 16384;
        gload_lds16(src + (size_t)tid * 8,        &lds[slot][tid * 8]);
        gload_lds16(src + 4096 + (size_t)tid * 8, &lds[slot][4096 + tid * 8]);
    };

    auto writeA = [&](const float4& v4, int slot) {
        u32 u0 = __float_as_uint(v4.x), u1 = __float_as_uint(v4.y);
        u32 u2 = __float_as_uint(v4.z), u3 = __float_as_uint(v4.w);
        u32 h01 = (u0 >> 16) | (u1 & 0xffff0000u);
        u32 h23 = (u2 >> 16) | (u3 & 0xffff0000u);
        float r0 = v4.x - __uint_as_float(u0 & 0xffff0000u);
        float r1 = v4.y - __uint_as_float(u1 & 0xffff0000u);
        float r2 = v4.z - __uint_as_float(u2 & 0xffff0000u);
        float r3 = v4.w - __uint_as_float(u3 & 0xffff0000u);
        u32 l01, l23;
        asm("v_cvt_pk_bf16_f32 %0, %1, %2" : "=v"(l01) : "v"(r0), "v"(r1));
        asm("v_cvt_pk_bf16_f32 %0, %1, %2" : "=v"(l23) : "v"(r2), "v"(r3));
        uint2 hv = {h01, h23}, lv = {l01, l23};
        const int off = A_HI + akg_w * 520 + xrow * 8 + ajh;
        *(uint2*)&lds[slot][off]        = hv;
        *(uint2*)&lds[slot][off + 2080] = lv;
    };

    auto comp = [&](int slot) {
        const unsigned short* L = lds[slot];
        short8 ah[2], al[2];
        #pragma unroll
        for (int m = 0; m < 2; ++m) {
            const int roff = A_HI + akg * 520 + (wrow * 32 + m * 16 + arow) * 8;
            ah[m] = *(const short8*)&L[roff];
            al[m] = *(const short8*)&L[roff + 2080];
        }
        #pragma unroll
        for (int nf = 0; nf < 2; ++nf) {
            const int n = wcol * 32 + nf * 16 + arow;
            short8 bh = *(const short8*)&L[akg * 1024 + n * 8];
            short8 bl = *(const short8*)&L[4096 + akg * 1024 + n * 8];
            #pragma unroll
            for (int m = 0; m < 2; ++m) {
                acc[m][nf] = __builtin_amdgcn_mfma_f32_16x16x32_bf16(ah[m], bh, acc[m][nf], 0, 0, 0);
                acc[m][nf] = __builtin_amdgcn_mfma_f32_16x16x32_bf16(ah[m], bl, acc[m][nf], 0, 0, 0);
                acc[m][nf] = __builtin_amdgcn_mfma_f32_16x16x32_bf16(al[m], bh, acc[m][nf], 0, 0, 0);
            }
        }
    };

    xr0 = *(const float4*)(xg);
    xr1 = *(const float4*)(xg + 32);
    xr2 = *(const float4*)(xg + 64);
    __builtin_amdgcn_sched_barrier(0);
    gloadB(0, 0);
    gloadB(1, 1);
    __builtin_amdgcn_sched_barrier(0);
    asm volatile("s_waitcnt vmcnt(0)" ::: "memory");
    writeA(xr0, 0);
    asm volatile("s_waitcnt lgkmcnt(0)" ::: "memory");
    asm volatile("s_barrier" ::: "memory");

#define STEPA(C, I, XW, XL) {                                                 \
    asm volatile("s_waitcnt vmcnt(3)" ::: "memory");                          \
    writeA(XW, ((I) + 1) % 3);                                                \
    asm volatile("s_waitcnt lgkmcnt(0)" ::: "memory");                        \
    asm volatile("s_barrier" ::: "memory");                                   \
    { int cx = (C) + 3; if (cx > kc - 1) cx = kc - 1;                         \
      XL = *(const float4*)(xg + (size_t)cx * 32); }                          \
    __builtin_amdgcn_sched_barrier(0);                                        \
    { int cbv = (C) + 2; if (cbv > kc - 1) cbv = kc - 1;                      \
      gloadB(cbv, ((I) + 2) % 3); }                                           \
    __builtin_amdgcn_sched_barrier(0);                                        \
    comp(I); }

    const int m3 = kc - (kc % 3);
    for (int c = 0; c < m3; c += 3) {
        STEPA(c,     0, xr1, xr0);
        STEPA(c + 1, 1, xr2, xr1);
        STEPA(c + 2, 2, xr0, xr2);
    }
#undef STEPA

    for (int t = m3; t < kc; ++t) {
        float4 xt = *(const float4*)(xg + (size_t)t * 32);
        asm volatile("s_waitcnt vmcnt(0)" ::: "memory");
        __syncthreads();
        writeA(xt, t % 3);
        asm volatile("s_waitcnt lgkmcnt(0)" ::: "memory");
        __syncthreads();
        comp(t % 3);
    }

    float* o = ks ? dst1 : dst0;
    #pragma unroll
    for (int m = 0; m < 2; ++m)
        #pragma unroll
        for (int nf = 0; nf < 2; ++nf) {
            const int col = cb + wcol * 32 + nf * 16 + arow;
            const int r0  = rb + wrow * 32 + m * 16 + akg * 4;
            #pragma unroll
            for (int r = 0; r < 4; ++r)
                o[(size_t)(r0 + r) * N_EXP + col] = acc[m][nf][r];
        }
}

// ============ p1 fallback (fp32 VALU, proven r5) ============================
#define F1_BM 32
#define F1_BN 64
#define F1_BK 32
#define F1_NT (K_DIM / F1_BK)

__global__ __launch_bounds__(256, 4) void p1_fp32(
    const float* __restrict__ x, const float* __restrict__ W,
    float* __restrict__ logits)
{
    __shared__ float xs[2][F1_BK * F1_BM];
    __shared__ float ws[2][F1_BK * F1_BN];

    const int tid  = threadIdx.x;
    const int w    = tid >> 6;
    const int lane = tid & 63;
    const int trow = tid >> 5;
    const int tcol = tid & 31;
    const int rb   = blockIdx.y * F1_BM;
    const int cb   = blockIdx.x * F1_BN;

    float acc[4][2] = {};
    const float* gx[4];
    const float* gw[2];
    #pragma unroll
    for (int q = 0; q < 4; ++q) {
        int L = (w * 4 + q) * 64 + lane;
        gx[q] = x + (size_t)(rb + (L & 31)) * K_DIM + (L >> 5);
    }
    #pragma unroll
    for (int q = 0; q < 2; ++q) {
        int F = ((w * 2 + q) * 64 + lane) * 4;
        gw[q] = W + (size_t)(F >> 6) * N_EXP + cb + (F & 63);
    }
    auto stage = [&](int buf) {
        #pragma unroll
        for (int q = 0; q < 2; ++q) gload_lds16(gw[q], &ws[buf][(w * 2 + q) * 256]);
        #pragma unroll
        for (int q = 0; q < 4; ++q) gload_lds4(gx[q], &xs[buf][(w * 4 + q) * 64]);
        #pragma unroll
        for (int q = 0; q < 2; ++q) gw[q] += (size_t)F1_BK * N_EXP;
        #pragma unroll
        for (int q = 0; q < 4; ++q) gx[q] += F1_BK;
    };
    auto compute = [&](int buf) {
        #pragma unroll
        for (int kk = 0; kk < F1_BK; ++kk) {
            float4 av = *(const float4*)&xs[buf][kk * 32 + trow * 4];
            float2 bv = *(const float2*)&ws[buf][kk * 64 + tcol * 2];
            float aa[4] = {av.x, av.y, av.z, av.w};
            float bb[2] = {bv.x, bv.y};
            #pragma unroll
            for (int i = 0; i < 4; ++i)
                #pragma unroll
                for (int jq = 0; jq < 2; ++jq)
                    acc[i][jq] = fmaf(aa[i], bb[jq], acc[i][jq]);
        }
    };
    stage(0);
    asm volatile("s_waitcnt vmcnt(0)" ::: "memory");
    __syncthreads();
    int cur = 0;
    for (int t = 0; t < F1_NT; ++t) {
        if (t + 1 < F1_NT) stage(cur ^ 1);
        compute(cur);
        asm volatile("s_waitcnt vmcnt(0)" ::: "memory");
        __syncthreads();
        cur ^= 1;
    }
    #pragma unroll
    for (int i = 0; i < 4; ++i) {
        float2 o = {acc[i][0], acc[i][1]};
        *(float2*)(logits + (size_t)(rb + trow * 4 + i) * N_EXP + cb + tcol * 2) = o;
    }
}

// ============ p2: sum npart partials + route + flag (1 wave / row) ==========
__global__ __launch_bounds__(256) void p2_route(
    float* __restrict__ sc, const float* __restrict__ pk1,
    const float* __restrict__ pk2, const float* __restrict__ pk3,
    const float* __restrict__ bias,
    float* __restrict__ out_idx, float* __restrict__ out_w,
    int* __restrict__ flag_cnt, int* __restrict__ flag_list,
    int npart, float thS, float thG)
{
    const int lane = threadIdx.x & 63;
    const int row  = blockIdx.x * 4 + (threadIdx.x >> 6);
    float* s = sc + (size_t)row * N_EXP;
    const int ib = lane * 4;

    float4 l4 = *(const float4*)&s[ib];
    if (npart >= 2) {
        float4 o4 = *(const float4*)(pk1 + (size_t)row * N_EXP + ib);
        l4.x += o4.x; l4.y += o4.y; l4.z += o4.z; l4.w += o4.w;
    }
    if (npart >= 4) {
        float4 o4 = *(const float4*)(pk2 + (size_t)row * N_EXP + ib);
        l4.x += o4.x; l4.y += o4.y; l4.z += o4.z; l4.w += o4.w;
        float4 p4 = *(const float4*)(pk3 + (size_t)row * N_EXP + ib);
        l4.x += p4.x; l4.y += p4.y; l4.z += p4.z; l4.w += p4.w;
    }
    float4 s4;
    s4.x = 1.0f / (1.0f + expf(-l4.x));
    s4.y = 1.0f / (1.0f + expf(-l4.y));
    s4.z = 1.0f / (1.0f + expf(-l4.z));
    s4.w = 1.0f / (1.0f + expf(-l4.w));
    *(float4*)&s[ib] = s4;

    float4 b4 = *(const float4*)&bias[ib];
    float v0 = s4.x + b4.x, v1 = s4.y + b4.y, v2 = s4.z + b4.z, v3 = s4.w + b4.w;

    float a = fmaxf(v0, v1), b = fminf(v0, v1);
    float c = fmaxf(v2, v3), d = fminf(v2, v3);
    float m1 = fmaxf(a, c);
    float m2 = fmaxf(fminf(a, c), fmaxf(b, d));
    #pragma unroll
    for (int off = 1; off <= 4; off <<= 1) {
        float o1 = __shfl_xor(m1, off);
        float o2 = __shfl_xor(m2, off);
        float hi = fmaxf(m1, o1), lo = fminf(m1, o1);
        m2 = fmaxf(lo, fmaxf(m2, o2));
        m1 = hi;
    }
    float gsum = m1 + m2;
    float gv[8];
    #pragma unroll
    for (int g = 0; g < 8; ++g) gv[g] = __shfl(gsum, g * 8);

    unsigned gmask = 0;
    float g4 = 0.f, g5 = 0.f;
    #pragma unroll
    for (int t = 0; t < 5; ++t) {
        float best = -INFINITY; int bg = 0;
        #pragma unroll
        for (int g = 0; g < 8; ++g)
            if (!((gmask >> g) & 1) && gv[g] > best) { best = gv[g]; bg = g; }
        if (t < 4) { gmask |= 1u << bg; if (t == 3) g4 = best; }
        else g5 = best;
    }
    bool flag = (g4 - g5) < thG;

    bool sel = (gmask >> (lane >> 3)) & 1;
    float c0 = sel ? v0 : -INFINITY;
    float c1 = sel ? v1 : -INFINITY;
    float c2 = sel ? v2 : -INFINITY;
    float c3 = sel ? v3 : -INFINITY;

    float tvv[9]; int tii[9];
    #pragma unroll
    for (int r = 0; r < 9; ++r) {
        float lv = c0; int li = ib;
        if (c1 > lv) { lv = c1; li = ib + 1; }
        if (c2 > lv) { lv = c2; li = ib + 2; }
        if (c3 > lv) { lv = c3; li = ib + 3; }
        #pragma unroll
        for (int off = 1; off < 64; off <<= 1) {
            float ov = __shfl_xor(lv, off);
            int   oi = __shfl_xor(li, off);
            if (ov > lv || (ov == lv && oi < li)) { lv = ov; li = oi; }
        }
        tvv[r] = lv; tii[r] = li;
        if      (li == ib)     c0 = -INFINITY;
        else if (li == ib + 1) c1 = -INFINITY;
        else if (li == ib + 2) c2 = -INFINITY;
        else if (li == ib + 3) c3 = -INFINITY;
    }
    #pragma unroll
    for (int k = 0; k < 8; ++k)
        if (tvv[k] - tvv[k + 1] < thS) flag = true;

    float wv[8]; double wsum = 0.0;
    #pragma unroll
    for (int k = 0; k < 8; ++k) {
        int t = tii[k];
        int jq = t & 3;
        float svv = (jq == 0) ? s4.x : (jq == 1) ? s4.y : (jq == 2) ? s4.z : s4.w;
        float wk = __shfl(svv, t >> 2);
        wv[k] = wk; wsum += (double)wk;
    }
    double inv = 2.5 / (wsum + 1e-20);
    if (lane == 0) {
        #pragma unroll
        for (int k = 0; k < 8; ++k) {
            out_idx[(size_t)row * 8 + k] = (float)tii[k];
            out_w[(size_t)row * 8 + k]   = (float)((double)wv[k] * inv);
        }
        if (flag) {
            int pz = atomicAdd(flag_cnt, 1);
            if (pz < FLAG_CAP) flag_list[pz] = row;
        }
    }
}

// ============ p3a: fp64 partials, block = (slot, K-slice) — r13 proven ======
#define P3_SL 8
#define P3_SK (K_DIM / P3_SL)   // 896
#define P3_QK (P3_SK / 4)       // 224

__global__ __launch_bounds__(256) void p3a_partial(
    const float* __restrict__ x, const float* __restrict__ W,
    const int* __restrict__ flag_cnt, const int* __restrict__ flag_list,
    double* __restrict__ partials, int cap)
{
    const int slot  = blockIdx.x >> 3;
    const int slice = blockIdx.x & 7;
    int count = *flag_cnt;
    if (count > cap) count = cap;
    if (slot >= count) return;
    const int row = flag_list[slot];
    const int tid = threadIdx.x;          // expert e

    __shared__ float xls[P3_SK];
    if (tid < P3_QK)
        *(float4*)&xls[tid * 4] =
            *(const float4*)(x + (size_t)row * K_DIM + slice * P3_SK + tid * 4);
    __syncthreads();

    const float* wp = W + (size_t)(slice * P3_SK) * N_EXP + tid;
    double a0 = 0.0, a1 = 0.0, a2 = 0.0, a3 = 0.0;
    #pragma unroll 2
    for (int j = 0; j < P3_QK; ++j) {
        a0 = fma((double)xls[j],            (double)wp[(size_t)j * N_EXP],              a0);
        a1 = fma((double)xls[j + P3_QK],    (double)wp[(size_t)(j + P3_QK) * N_EXP],    a1);
        a2 = fma((double)xls[j + 2*P3_QK],  (double)wp[(size_t)(j + 2*P3_QK) * N_EXP],  a2);
        a3 = fma((double)xls[j + 3*P3_QK],  (double)wp[(size_t)(j + 3*P3_QK) * N_EXP],  a3);
    }
    partials[((size_t)slot * P3_SL + slice) * N_EXP + tid] = (a0 + a1) + (a2 + a3);
}

// ============ p3b: reduce + fp64 route, 1 block / slot — r13 proven =========
__global__ __launch_bounds__(256) void p3b_route(
    const double* __restrict__ partials, const float* __restrict__ bias,
    float* __restrict__ out_idx, float* __restrict__ out_w,
    const int* __restrict__ flag_cnt, const int* __restrict__ flag_list, int cap)
{
    const int slot = blockIdx.x;
    int count = *flag_cnt;
    if (count > cap) count = cap;
    if (slot >= count) return;
    const int row = flag_list[slot];
    const int tid = threadIdx.x;

    __shared__ double scl[N_EXP];
    __shared__ float  bias_s[N_EXP];
    bias_s[tid] = bias[tid];

    const double* pp = partials + (size_t)slot * P3_SL * N_EXP + tid;
    double l = 0.0;
    #pragma unroll
    for (int sx = 0; sx < P3_SL; ++sx) l += pp[(size_t)sx * N_EXP];
    scl[tid] = 1.0 / (1.0 + exp(-l));
    __syncthreads();
    if (tid >= 64) return;

    const int lane = tid;
    const int ib = lane * 4;
    double s0 = scl[ib], s1 = scl[ib + 1], s2 = scl[ib + 2], s3 = scl[ib + 3];
    double v0 = s0 + (double)bias_s[ib];
    double v1 = s1 + (double)bias_s[ib + 1];
    double v2 = s2 + (double)bias_s[ib + 2];
    double v3 = s3 + (double)bias_s[ib + 3];

    double a = fmax(v0, v1), b = fmin(v0, v1);
    double c = fmax(v2, v3), d = fmin(v2, v3);
    double m1 = fmax(a, c);
    double m2 = fmax(fmin(a, c), fmax(b, d));
    #pragma unroll
    for (int off = 1; off <= 4; off <<= 1) {
        double o1 = __shfl_xor(m1, off);
        double o2 = __shfl_xor(m2, off);
        double hi = fmax(m1, o1), lo = fmin(m1, o1);
        m2 = fmax(lo, fmax(m2, o2));
        m1 = hi;
    }
    double gsum = m1 + m2;
    double gvv[8];
    #pragma unroll
    for (int g = 0; g < 8; ++g) gvv[g] = __shfl(gsum, g * 8);

    unsigned gmask = 0;
    #pragma unroll
    for (int t = 0; t < 4; ++t) {
        double best = -1e300; int bg = 0;
        #pragma unroll
        for (int g = 0; g < 8; ++g)
            if (!((gmask >> g) & 1) && gvv[g] > best) { best = gvv[g]; bg = g; }
        gmask |= 1u << bg;
    }

    bool sel = (gmask >> (lane >> 3)) & 1;
    double c0 = sel ? v0 : -1e300;
    double c1 = sel ? v1 : -1e300;
    double c2 = sel ? v2 : -1e300;
    double c3 = sel ? v3 : -1e300;

    int tii[8];
    #pragma unroll
    for (int r = 0; r < 8; ++r) {
        double lv = c0; int li = ib;
        if (c1 > lv) { lv = c1; li = ib + 1; }
        if (c2 > lv) { lv = c2; li = ib + 2; }
        if (c3 > lv) { lv = c3; li = ib + 3; }
        #pragma unroll
        for (int off = 1; off < 64; off <<= 1) {
            double ov = __shfl_xor(lv, off);
            int    oi = __shfl_xor(li, off);
            if (ov > lv || (ov == lv && oi < li)) { lv = ov; li = oi; }
        }
        tii[r] = li;
        if      (li == ib)     c0 = -1e300;
        else if (li == ib + 1) c1 = -1e300;
        else if (li == ib + 2) c2 = -1e300;
        else if (li == ib + 3) c3 = -1e300;
    }

    double wv[8]; double wsum = 0.0;
    #pragma unroll
    for (int k = 0; k < 8; ++k) {
        int t = tii[k];
        int jq = t & 3;
        double svv = (jq == 0) ? s0 : (jq == 1) ? s1 : (jq == 2) ? s2 : s3;
        double wk = __shfl(svv, t >> 2);
        wv[k] = wk; wsum += wk;
    }
    double inv = 2.5 / (wsum + 1e-20);
    if (lane == 0) {
        #pragma unroll
        for (int k = 0; k < 8; ++k) {
            out_idx[(size_t)row * 8 + k] = (float)tii[k];
            out_w[(size_t)row * 8 + k]   = (float)(wv[k] * inv);
        }
    }
}

extern "C" void kernel_launch(void* const* d_in, const int* in_sizes, int n_in,
                              void* d_out, int out_size, void* d_ws, size_t ws_size,
                              hipStream_t stream) {
    const float* x    = (const float*)d_in[0];
    const float* W    = (const float*)d_in[1];
    const float* bias = (const float*)d_in[2];

    float* out     = (float*)d_out;
    float* out_idx = out;
    float* out_w   = out + N_ROWS * 8;
    float* out_s   = out + N_ROWS * 16;

    int* flag_cnt  = (int*)d_ws;
    int* flag_list = (int*)d_ws + 4;

    const size_t WIMG_OFF  = 65536;
    const size_t WIMG_SIZE = (size_t)NTALL * 32768;        // 7.0 MiB
    const size_t PK_OFF    = WIMG_OFF + WIMG_SIZE;
    const size_t PK_SIZE   = (size_t)N_ROWS * N_EXP * 4;   // 8 MiB

    bool m4 = ws_size >= PK_OFF + 3 * PK_SIZE;
    bool m2 = ws_size >= PK_OFF + PK_SIZE;
    bool m1 = ws_size >= PK_OFF;

    long long avail = (long long)ws_size - (long long)PK_OFF;
    int cap = (avail > 0) ? (int)(avail / (P3_SL * N_EXP * sizeof(double))) : 0;
    if (cap > FLAG_CAP) cap = FLAG_CAP;

    (void)hipMemsetAsync(flag_cnt, 0, sizeof(int), stream);

    unsigned short* wimg = (unsigned short*)((char*)d_ws + WIMG_OFF);
    float* pk1 = (float*)((char*)d_ws + PK_OFF);
    float* pk2 = pk1 + (size_t)N_ROWS * N_EXP;
    float* pk3 = pk2 + (size_t)N_ROWS * N_EXP;

    if (m4) {
        p0_wprep<<<NTALL * 8, 128, 0, stream>>>(W, wimg);
        p1_mfma2<<<512, 512, 0, stream>>>(x, wimg, out_s, pk1, pk2, pk3);
        p2_route<<<N_ROWS / 4, 256, 0, stream>>>(out_s, pk1, pk2, pk3, bias,
                                                 out_idx, out_w, flag_cnt, flag_list,
                                                 4, 1.2e-5f, 2.4e-5f);
    } else if (m2) {
        p0_wprep<<<NTALL * 8, 128, 0, stream>>>(W, wimg);
        p1_mfma<<<512, 512, 0, stream>>>(x, wimg, out_s, pk1, 1);
        p2_route<<<N_ROWS / 4, 256, 0, stream>>>(out_s, pk1, pk1, pk1, bias,
                                                 out_idx, out_w, flag_cnt, flag_list,
                                                 2, 1.2e-5f, 2.4e-5f);
    } else if (m1) {
        p0_wprep<<<NTALL * 8, 128, 0, stream>>>(W, wimg);
        p1_mfma<<<256, 512, 0, stream>>>(x, wimg, out_s, out_s, 0);
        p2_route<<<N_ROWS / 4, 256, 0, stream>>>(out_s, out_s, out_s, out_s, bias,
                                                 out_idx, out_w, flag_cnt, flag_list,
                                                 1, 1.2e-5f, 2.4e-5f);
    } else {
        dim3 g1(N_EXP / F1_BN, N_ROWS / F1_BM);
        p1_fp32<<<g1, 256, 0, stream>>>(x, W, out_s);
        p2_route<<<N_ROWS / 4, 256, 0, stream>>>(out_s, out_s, out_s, out_s, bias,
                                                 out_idx, out_w, flag_cnt, flag_list,
                                                 1, 6e-6f, 1.2e-5f);
    }

    if (cap >= 64) {
        double* partials = (double*)((char*)d_ws + PK_OFF);
        p3a_partial<<<cap * P3_SL, 256, 0, stream>>>(x, W, flag_cnt, flag_list,
                                                     partials, cap);
        p3b_route<<<cap, 256, 0, stream>>>(partials, bias, out_idx, out_w,
                                           flag_cnt, flag_list, cap);
    }
}